// Round 12
// baseline (1170.015 us; speedup 1.0000x reference)
//
#include <hip/hip_runtime.h>
#include <math.h>

// ---------------------------------------------------------------------------
// HFPS: CNN (4 residual blocks, circular 3x3 conv, 48x48, 64ch) ->
//       A = [[Fvv[n][:,n], Fvh_n],[-Fvh_n^T, Fhh_a]] (1048x1048 skew) ->
//       sign(Pf(A)), log|Pf(A)| + log_J
// Pfaffian via unpivoted blocked skew LDL^T with 2x2 pivots, fp64.
//   Pf = prod(t_p); log|Pf| = sum log|t_p| = 0.5*slogdet(A).
//
// R12 (R11 post-mortem: all kernels <51us; time = 45 serial dispatches,
// 33 of them the Pfaffian chain. R9 proved R7's fused phases R/T/barriers
// cost only ~5us/panel -- D at ~62us/panel was the whole problem, and
// R10's factor_lds does it in <10us):
//   -> re-fuse the Pfaffian into ONE cooperative kernel (R7 distributed-A
//      structure, proven) with factor_lds as phase D (proven).
//   - A built by parallel dispatches (buildAvv tile-transpose, buildAs);
//     k_pf gathers its rows from A with coalesced cached reads.
//   - cross-block surfaces (Pk panels, Dk diag tiles) via relaxed
//     agent-scope bypass stores + fresh-range cached reads (proven R5/R7).
//   - fence-free flag barrier (proven R5/R7), 2 barriers/panel, 33 total.
//   CNN side unchanged from R11.
//
// Workspace layout:
//   0: flags[256]   1024: logJ acc   1088: nidx[1024]
//   8192:  hist scratch unused; 74240: tbuf/ybuf/hbuf0/hbuf1 (CNN)
//   2433536: A (8.79 MB)   5537536(A+3.1MB region): Pk buffers after A:
//   A:      2433536 .. 11220288
//   Pbase:  11220992 (<=4,128,768 B)
//   Dbase:  15349760 (17*64*64*8 = 557,056 B)   total ~15.9 MB
// ---------------------------------------------------------------------------

#define NPIX 2304          // 48*48
#define MSZ  4608          // 2*48*48
#define NOCC 1024
#define NHID 24
#define PF_N 1048          // NOCC + 2*NHID
#define PF_BLOCKS 256
#define NPAN 17            // 16 panels of 64 + final 24

__device__ __forceinline__ float gelu_f(float v){
  // jax.nn.gelu approximate=True (tanh form)
  float v3 = v*v*v;
  return 0.5f*v*(1.0f + tanhf(0.7978845608028654f*(v + 0.044715f*v3)));
}

// coherent (cache-bypassing) store: relaxed agent-scope atomic (R5).
__device__ __forceinline__ void ast(double* p, double v){
  __hip_atomic_store(p, v, __ATOMIC_RELAXED, __HIP_MEMORY_SCOPE_AGENT);
}

// ---- occupied indices (sorted) + block-0 pre (t = x/sqrt(2)) ----
__global__ void k_prep(const float* __restrict__ x, int* __restrict__ nidx,
                       float* __restrict__ tbuf){
  __shared__ int cnt[256];
  __shared__ int off[256];
  int t = threadIdx.x;
  int c = 0;
  for (int k = 0; k < 18; k++){
    int idx = t*18 + k;
    float v = x[idx];
    c += (v == 1.0f) ? 1 : 0;
    tbuf[idx] = v * 0.70710678118654752f;
  }
  cnt[t] = c;
  __syncthreads();
  if (t == 0){ int s = 0; for (int q=0;q<256;q++){ off[q]=s; s+=cnt[q]; } }
  __syncthreads();
  int o = off[t];
  for (int k = 0; k < 18; k++){
    int idx = t*18+k;
    if (x[idx] == 1.0f) nidx[o++] = idx;
  }
}

// ---- circular 3x3 conv, 3 px/thread, fused bias/gelu/res/scale/pre/logJ ----
__global__ __launch_bounds__(128) void k_conv(const float* __restrict__ in,
      const float* __restrict__ wgt, const float* __restrict__ bias,
      const float* __restrict__ res, float* __restrict__ outp,
      float* __restrict__ pre_out, double* __restrict__ logJ_acc,
      int cin, int resmode, int dogelu, float scale, float pre_scale){
  const int c  = blockIdx.x / 6;
  const int rg = blockIdx.x % 6;
  const int tid = threadIdx.x;
  const int y  = rg*8 + (tid >> 4);
  const int xg = (tid & 15)*3;
  const int ym = ((y+47)%48)*48, y0 = y*48, yp = ((y+1)%48)*48;
  int c5[5];
  #pragma unroll
  for (int t = 0; t < 5; t++){
    int xx = xg - 1 + t;
    c5[t] = (xx < 0) ? 47 : ((xx >= 48) ? xx - 48 : xx);
  }
  float s0 = 0.f, s1 = 0.f, s2 = 0.f;
  const float* wp = wgt + c*cin*9;
  for (int ci = 0; ci < cin; ci++){
    const float* b_ = in + ci*NPIX;
    #pragma unroll
    for (int rr = 0; rr < 3; rr++){
      const int rb = (rr == 0) ? ym : ((rr == 1) ? y0 : yp);
      float v0 = b_[rb+c5[0]], v1 = b_[rb+c5[1]], v2 = b_[rb+c5[2]];
      float v3 = b_[rb+c5[3]], v4 = b_[rb+c5[4]];
      float w0 = wp[3*rr], w1 = wp[3*rr+1], w2 = wp[3*rr+2];
      s0 += v0*w0 + v1*w1 + v2*w2;
      s1 += v1*w0 + v2*w1 + v3*w2;
      s2 += v2*w0 + v3*w1 + v4*w2;
    }
    wp += 9;
  }
  const float bv = bias ? bias[c] : 0.f;
  const int base = c*NPIX + y0 + xg;
  float sv[3] = {s0, s1, s2};
  double ls = 0.0;
  #pragma unroll
  for (int t = 0; t < 3; t++){
    float s = sv[t] + bv;
    if (dogelu) s = gelu_f(s);
    if (resmode == 1) s += res[c*NPIX + y0 + xg + t];
    else if (resmode == 2) s += res[(c>>5)*NPIX + y0 + xg + t];
    s *= scale;
    outp[base+t] = s;
    if (pre_out) pre_out[base+t] = gelu_f(s * pre_scale);
    ls += (double)s;
  }
  if (logJ_acc && c >= 48){
    for (int o = 32; o > 0; o >>= 1) ls += __shfl_down(ls, o, 64);
    if ((tid & 63) == 0) atomicAdd(logJ_acc, ls);
  }
}

// ---- build A lower triangle, vv part: 32x32 LDS tile transpose ----
__global__ __launch_bounds__(256) void k_buildAvv(const float* __restrict__ Fvv,
      const int* __restrict__ nidx, double* __restrict__ A){
  __shared__ float G1[32][33], G2[32][33];
  __shared__ int sNi[32], sNj[32];
  int I = 0, item = blockIdx.x;          // 528 lower tiles of 1024/32
  while ((I+1)*(I+2)/2 <= item) I++;
  const int J = item - I*(I+1)/2;
  const int i0 = I*32, j0 = J*32;
  const int tid = threadIdx.x;
  if (tid < 32){ sNi[tid] = nidx[i0+tid]; }
  else if (tid < 64){ sNj[tid-32] = nidx[j0+tid-32]; }
  __syncthreads();
  for (int idx = tid; idx < 32*32; idx += 256){
    const int r = idx >> 5, c = idx & 31;
    G1[r][c] = Fvv[(size_t)sNi[r]*MSZ + sNj[c]];
    G2[r][c] = Fvv[(size_t)sNj[r]*MSZ + sNi[c]];
  }
  __syncthreads();
  for (int idx = tid; idx < 32*32; idx += 256){
    const int r = idx >> 5, c = idx & 31;
    const int i = i0 + r, j = j0 + c;
    if (i > j)
      A[(size_t)i*PF_N + j] = 0.5*((double)G1[r][c] - (double)G2[c][r]);
  }
}

// ---- build A strips: rows 1024..1047 (vh gather + hh) ----
__global__ void k_buildAs(const float* __restrict__ Fhh,
      const float* __restrict__ hfin, const int* __restrict__ nidx,
      double* __restrict__ A){
  int g = blockIdx.x*256 + threadIdx.x;
  if (g >= 24*PF_N) return;
  const int i = NOCC + g / PF_N, j = g % PF_N;
  if (j >= i) return;
  const int r = i - NOCC;
  double v;
  if (j < NOCC){
    int nj = nidx[j];
    int ss = (nj >= NPIX) ? 1 : 0;
    v = -(double)hfin[(2*r+ss)*NPIX + (nj - ss*NPIX)];
  } else {
    int r2 = j - NOCC;
    v = 0.5*((double)Fhh[r*NHID + r2] - (double)Fhh[r2*NHID + r]);
  }
  A[(size_t)i*PF_N + j] = v;
}

// ---- fence-free flag-array grid barrier (proven R5/R7) ----
__device__ __forceinline__ void gridbar(unsigned* flags, unsigned ep){
  __syncthreads();                 // each wave: s_waitcnt vmcnt(0) + barrier
  const int tid = threadIdx.x;
  if (tid == 0){
    asm volatile("" ::: "memory");
    __builtin_amdgcn_s_waitcnt(0);
    __hip_atomic_store(&flags[blockIdx.x], ep, __ATOMIC_RELAXED,
                       __HIP_MEMORY_SCOPE_AGENT);
  }
  if (tid < 64){
    for (;;){
      unsigned v0 = __hip_atomic_load(&flags[tid      ], __ATOMIC_RELAXED, __HIP_MEMORY_SCOPE_AGENT);
      unsigned v1 = __hip_atomic_load(&flags[tid +  64], __ATOMIC_RELAXED, __HIP_MEMORY_SCOPE_AGENT);
      unsigned v2 = __hip_atomic_load(&flags[tid + 128], __ATOMIC_RELAXED, __HIP_MEMORY_SCOPE_AGENT);
      unsigned v3 = __hip_atomic_load(&flags[tid + 192], __ATOMIC_RELAXED, __HIP_MEMORY_SCOPE_AGENT);
      bool ok = (v0 >= ep) & (v1 >= ep) & (v2 >= ep) & (v3 >= ep);
      if (__all(ok)) break;
      __builtin_amdgcn_s_sleep(1);
    }
    asm volatile("" ::: "memory");
  }
  __syncthreads();
}

// Pk offset in doubles: 64 * sum_{k'<k} (984 - 64k')
__device__ __forceinline__ size_t pk_off(int k){
  return (size_t)64 * ((size_t)984*(size_t)k - (size_t)32*(size_t)k*(size_t)(k-1));
}

// ---- fused distributed-A Pfaffian: R7 structure + fast factor_lds D ----
// Block b owns rows {b, b+256, b+512, b+768} (+ b+1024 if b<24) in LDS.
__global__ __launch_bounds__(256) void k_pf(const double* __restrict__ A,
      double* __restrict__ Pbase, double* __restrict__ Dbase,
      unsigned* __restrict__ flags, const double* __restrict__ logJ,
      float* __restrict__ outp){
  const int N = PF_N;
  const int tid = threadIdx.x;
  const int b = blockIdx.x;
  const int nrows = (b < 24) ? 5 : 4;

  __shared__ double rowbuf[2688];   // owned rows, cols 0..i-1 packed
  __shared__ double Dt[64*65];      // diag tile (lower) for factor_lds
  __shared__ double sAA[32][64];    // a_c * invt history
  __shared__ double sBB[32][64];    // b_c * invt history
  __shared__ double sInvL[32], sTf[32];
  __shared__ double sCA[5][32], sCB[5][32];

  #define RIDX(s)  (b + 256*(s))
  #define ROFF(s)  ((s)*b + 128*(s)*((s)-1))

  // ---- gather own rows from A (coalesced cached reads) ----
  for (int s = 0; s < nrows; s++){
    const int i = RIDX(s);
    const int o = ROFF(s);
    const double* Ar = A + (size_t)i*N;
    for (int j = tid; j < i; j += 256) rowbuf[o+j] = Ar[j];
  }
  __syncthreads();

  // ---- publish diag tile 0 (rows 0..63 owned by blocks 0..63, s=0) ----
  if (b < 64){
    for (int c = tid; c < b; c += 256)
      ast(&Dbase[(size_t)b*64 + c], rowbuf[c]);
  }
  unsigned ep = 0;
  gridbar(flags, ++ep);

  double lsum = 0.0; int nneg = 0;   // block 0 / thread 0

  for (int k = 0; k < NPAN; k++){
    const int c0  = 64*k;
    const int w   = (N - c0 < 64) ? (N - c0) : 64;
    const int np  = w >> 1;
    const int tc0 = c0 + w;
    const int m   = N - tc0;
    const double* Dk = Dbase + (size_t)k*4096;
    double* Pk = Pbase + pk_off(k);

    // ---- phase D: redundant fast lower-tri factorization (factor_lds) ----
    {
      for (int idx = tid; idx < 64*64; idx += 256){
        int r = idx >> 6, c = idx & 63;
        if (r > c && r < w) Dt[r*65+c] = Dk[r*64+c];
      }
      __syncthreads();
      const int r = tid & 63, qu = tid >> 6;
      for (int j = 0; j < np; j++){
        const int r0 = 2*j, r1 = r0 + 1;
        const double t = -Dt[r1*65 + r0];
        const double invt = 1.0 / t;
        if (tid == 0){ sTf[j] = t; sInvL[j] = invt; }
        const bool rowok = (r < w) && (r >= r0 + 2);
        if (rowok){
          const double ar = Dt[r*65 + r0], br = Dt[r*65 + r1];
          if (qu == 0){ sAA[j][r] = ar * invt; sBB[j][r] = br * invt; }
          const int lo = r0 + 2, hi = r;
          const int per = (hi - lo + 3) >> 2;
          const int cb = lo + qu*per;
          int ce = cb + per; if (ce > hi) ce = hi;
          for (int c = cb; c < ce; c++){
            const double ac = Dt[c*65 + r0], bc = Dt[c*65 + r1];
            Dt[r*65 + c] += (br*ac - ar*bc) * invt;
          }
        }
        __syncthreads();
      }
      if (b == 0 && tid < 64){
        double lv = 0.0; int sg = 0;
        if (tid < np){ double t = sTf[tid]; lv = log(fabs(t)); sg = (t<0.0)?1:0; }
        for (int o = 32; o > 0; o >>= 1){
          lv += __shfl_down(lv, o, 64);
          sg += __shfl_down(sg, o, 64);
        }
        if (tid == 0){ lsum += lv; nneg += sg; }
      }
    }

    // ---- phase R: own trailing rows' panel cols (local, shfl) + Pk publish --
    if (m > 0){               // m>0 implies w==64, np==32
      const int wv = tid >> 6, lc = tid & 63;
      for (int s = wv; s < nrows; s += 4){
        const int i = RIDX(s);
        if (i < tc0) continue;
        const int o = ROFF(s);
        double v = rowbuf[o + c0 + lc];
        #pragma unroll 8
        for (int j = 0; j < 32; j++){
          double a  = __shfl(v, 2*j,   64);
          double bb = __shfl(v, 2*j+1, 64);
          if (lc >= 2*j+2) v += bb*sAA[j][lc] - a*sBB[j][lc];
        }
        rowbuf[o + c0 + lc] = v;
        ast(&Pk[(size_t)(i - tc0)*64 + lc], v);
      }
      __syncthreads();
      // T coefficients: sCB = b_i*invt (x a_j), sCA = a_i*invt (x b_j)
      {
        const int s = tid >> 5, l = tid & 31;
        if (tid < 160 && s < nrows){
          const int i = RIDX(s);
          if (i >= tc0){
            const int o = ROFF(s);
            sCA[s][l] = rowbuf[o + c0 + 2*l    ] * sInvL[l];
            sCB[s][l] = rowbuf[o + c0 + 2*l + 1] * sInvL[l];
          }
        }
      }
    }
    gridbar(flags, ++ep);

    // ---- phase T: rank-64 update of own rows (Pk cached reads) ----
    if (m > 0){
      const int maxOwn = RIDX(nrows-1);
      for (int base = tc0; base < maxOwn; base += 256){
        const int j = base + tid;
        const bool jv = (j < maxOwn);
        double acc[5];
        #pragma unroll
        for (int s = 0; s < 5; s++){
          acc[s] = 0.0;
          if (s < nrows && jv && j < RIDX(s)) acc[s] = rowbuf[ROFF(s) + j];
        }
        if (jv){
          const double* pr = Pk + (size_t)(j - tc0)*64;  // fresh-range cached
          #pragma unroll 4
          for (int l = 0; l < 32; l++){
            double a  = pr[2*l];
            double bb = pr[2*l+1];
            #pragma unroll
            for (int s = 0; s < 5; s++)
              acc[s] += sCB[s][l]*a - sCA[s][l]*bb;
          }
          #pragma unroll
          for (int s = 0; s < 5; s++)
            if (s < nrows && j < RIDX(s)) rowbuf[ROFF(s) + j] = acc[s];
        }
      }
      __syncthreads();
      // publish next diag tile: rows in [tc0, tc0+64)
      for (int s = 0; s < nrows; s++){
        const int i = RIDX(s);
        if (i >= tc0 && i < tc0 + 64){
          double* Dn = Dbase + (size_t)(k+1)*4096 + (size_t)(i - tc0)*64;
          const int o = ROFF(s);
          for (int c = tid; c < i - tc0; c += 256)
            ast(&Dn[c], rowbuf[o + tc0 + c]);
        }
      }
    }
    gridbar(flags, ++ep);
  }

  if (b == 0 && tid == 0){
    outp[0] = (nneg & 1) ? -1.0f : 1.0f;
    outp[1] = (float)(lsum + logJ[0]);
  }
  #undef RIDX
  #undef ROFF
}

// ---------------------------------------------------------------------------
extern "C" void kernel_launch(void* const* d_in, const int* in_sizes, int n_in,
                              void* d_out, int out_size, void* d_ws, size_t ws_size,
                              hipStream_t stream){
  (void)in_sizes; (void)n_in; (void)out_size; (void)ws_size;
  const float* x   = (const float*)d_in[0];
  const float* Fvv = (const float*)d_in[1];
  const float* Fhh = (const float*)d_in[2];
  const float* w1[4] = {(const float*)d_in[3], (const float*)d_in[7],
                        (const float*)d_in[11], (const float*)d_in[15]};
  const float* b1[4] = {(const float*)d_in[4], (const float*)d_in[8],
                        (const float*)d_in[12], (const float*)d_in[16]};
  const float* w2[4] = {(const float*)d_in[5], (const float*)d_in[9],
                        (const float*)d_in[13], (const float*)d_in[17]};
  const float* b2[3] = {(const float*)d_in[6], (const float*)d_in[10],
                        (const float*)d_in[14]};

  char* ws = (char*)d_ws;
  unsigned* flags = (unsigned*)(ws + 0);        // 256 x u32
  double* logJa   = (double*)(ws + 1024);
  int*    nidx    = (int*)(ws + 1088);
  const size_t CB = 589824;  // 64*2304*4
  float* tbuf  = (float*)(ws + 74240);
  float* ybuf  = (float*)(ws + 74240 + CB);
  float* hbuf0 = (float*)(ws + 74240 + 2*CB);
  float* hbuf1 = (float*)(ws + 74240 + 3*CB);
  double* A     = (double*)(ws + 2433536);      // 8.79 MB
  double* Pbase = (double*)(ws + 11220992);     // <=4.13 MB
  double* Dbase = (double*)(ws + 15349760);     // 0.56 MB

  hipMemsetAsync(d_ws, 0, 2048, stream);        // flags + logJ acc
  k_prep<<<1,256,0,stream>>>(x, nidx, tbuf);

  // CNN (conv1: gelu; conv2: res + fused next-pre / final logJ)
  k_conv<<<384,128,0,stream>>>(tbuf, w1[0], b1[0], nullptr, ybuf,
                               nullptr, nullptr, 2, 0, 1, 1.0f, 0.f);
  k_conv<<<384,128,0,stream>>>(ybuf, w2[0], b2[0], x, hbuf0,
                               tbuf, nullptr, 64, 2, 0, 1.0f,
                               0.70710678118654752f);
  k_conv<<<384,128,0,stream>>>(tbuf, w1[1], b1[1], nullptr, ybuf,
                               nullptr, nullptr, 64, 0, 1, 1.0f, 0.f);
  k_conv<<<384,128,0,stream>>>(ybuf, w2[1], b2[1], hbuf0, hbuf1,
                               tbuf, nullptr, 64, 1, 0, 1.0f,
                               0.57735026918962576f);
  k_conv<<<384,128,0,stream>>>(tbuf, w1[2], b1[2], nullptr, ybuf,
                               nullptr, nullptr, 64, 0, 1, 1.0f, 0.f);
  k_conv<<<384,128,0,stream>>>(ybuf, w2[2], b2[2], hbuf1, hbuf0,
                               tbuf, nullptr, 64, 1, 0, 1.0f, 0.5f);
  k_conv<<<384,128,0,stream>>>(tbuf, w1[3], b1[3], nullptr, ybuf,
                               nullptr, nullptr, 64, 0, 1, 1.0f, 0.f);
  k_conv<<<384,128,0,stream>>>(ybuf, w2[3], nullptr, hbuf0, hbuf1,
                               nullptr, logJa, 64, 1, 0,
                               0.44721359549995794f, 0.f);

  k_buildAvv<<<528,256,0,stream>>>(Fvv, nidx, A);
  k_buildAs<<<(24*PF_N+255)/256,256,0,stream>>>(Fhh, hbuf1, nidx, A);

  k_pf<<<PF_BLOCKS,256,0,stream>>>(A, Pbase, Dbase, flags, logJa,
                                   (float*)d_out);
}